// Round 3
// baseline (266.275 us; speedup 1.0000x reference)
//
#include <hip/hip_runtime.h>

// nonlocal_channel_similarity: B=16, C=256, H=W=64 (N=HW=4096)
//   G_b = X_b X_b^T   (fp32 atomics, 128x128 MFMA tiles, ksplit 16)
//   s_b = rowsums(X_b) (fused into diagonal gram tiles)
//   Q = gw@Pw (bf16), E = gw.pb                     (k_mid blocks 0..511)
//   u = Tw s, v = Pw s                              (k_mid blocks 512..543)
//   P''_b = G_b Q^T via MFMA; term[rj] = sum_c Tw[r,c] P''[c,rj]
//   g = relu(term + tb_r*(gw_rj.v_b) + (u_r + N tb_r)*E + gb)   (k_p fused)
//   out = g @ dw^T + db                                          (k_out)

#define CC  256
#define NB  16
#define HWN 4096

typedef __attribute__((ext_vector_type(4))) float f32x4;
typedef __attribute__((ext_vector_type(8))) short bf16x8;

__device__ inline unsigned short f2bf(float f) {
  unsigned u = __float_as_uint(f);
  u += 0x7fff + ((u >> 16) & 1);   // round-to-nearest-even
  return (unsigned short)(u >> 16);
}

// ---------------- zero G (4 MB) + S (16 KB) ---------------------------------
__global__ __launch_bounds__(256) void k_zero(float4* __restrict__ p) {
  p[(size_t)blockIdx.x * 256 + threadIdx.x] = make_float4(0.f, 0.f, 0.f, 0.f);
}

// ---------------- Gram + row sums -------------------------------------------
// grid (4 tiles of 128x128, 16 ksplit, 16 batch) = 1024 blocks, 4 waves each
// -> 4 blocks/CU (LDS 36 KB), 16 waves/CU for latency hiding.
// Wave w owns rows [32w,32w+32) x all 128 cols: acc[2][8].
// Diagonal tiles stage A only (B==A) and fold in row sums.
__global__ __launch_bounds__(256, 4) void k_gram(const float* __restrict__ x,
                                                 float* __restrict__ G,
                                                 float* __restrict__ S) {
  const int tile = blockIdx.x, ks = blockIdx.y, b = blockIdx.z;
  const int I = tile >> 1, J = tile & 1;
  const bool diag = (I == J);
  const float* xa = x + (size_t)b * CC * HWN + (size_t)(128 * I) * HWN;
  const float* xb = x + (size_t)b * CC * HWN + (size_t)(128 * J) * HWN;

  __shared__ unsigned short As[128 * 72];
  __shared__ unsigned short Bs[128 * 72];

  const int tid = threadIdx.x, w = tid >> 6, lane = tid & 63;
  const int quad = lane >> 4, m15 = lane & 15;
  const int srow = tid >> 4;          // staging row base 0..15
  const int scol = (tid & 15) << 2;   // staging col (floats)

  f32x4 acc[2][8];
  #pragma unroll
  for (int t = 0; t < 2; ++t)
    #pragma unroll
    for (int c = 0; c < 8; ++c) acc[t][c] = (f32x4){0.f, 0.f, 0.f, 0.f};
  float rs[8] = {0.f, 0.f, 0.f, 0.f, 0.f, 0.f, 0.f, 0.f};

  const int k0 = ks * 256;
  for (int kc = k0; kc < k0 + 256; kc += 64) {
    __syncthreads();
    #pragma unroll
    for (int p = 0; p < 8; ++p) {
      const int row = p * 16 + srow;
      float4 av = *(const float4*)(xa + (size_t)row * HWN + kc + scol);
      *(ushort4*)&As[row * 72 + scol] =
          make_ushort4(f2bf(av.x), f2bf(av.y), f2bf(av.z), f2bf(av.w));
      if (diag) {
        rs[p] += av.x + av.y + av.z + av.w;
      } else {
        float4 bv = *(const float4*)(xb + (size_t)row * HWN + kc + scol);
        *(ushort4*)&Bs[row * 72 + scol] =
            make_ushort4(f2bf(bv.x), f2bf(bv.y), f2bf(bv.z), f2bf(bv.w));
      }
    }
    __syncthreads();
    const unsigned short* Bbase = diag ? As : Bs;
    #pragma unroll
    for (int kk = 0; kk < 64; kk += 32) {
      const int fo = kk + (quad << 3);
      bf16x8 a0 = *(const bf16x8*)&As[(32 * w + m15) * 72 + fo];
      bf16x8 a1 = *(const bf16x8*)&As[(32 * w + 16 + m15) * 72 + fo];
      #pragma unroll
      for (int ct = 0; ct < 8; ++ct) {
        bf16x8 bf = *(const bf16x8*)&Bbase[(16 * ct + m15) * 72 + fo];
        acc[0][ct] = __builtin_amdgcn_mfma_f32_16x16x32_bf16(a0, bf, acc[0][ct], 0, 0, 0);
        acc[1][ct] = __builtin_amdgcn_mfma_f32_16x16x32_bf16(a1, bf, acc[1][ct], 0, 0, 0);
      }
    }
  }

  // C/D layout: col = lane&15, row = quad*4 + reg (m89-verified).
  // Stagger ct order by ks so concurrent ksplit blocks hit different lines.
  float* Gb = G + ((size_t)b << 16);
  #pragma unroll
  for (int t = 0; t < 2; ++t)
    #pragma unroll
    for (int ct = 0; ct < 8; ++ct) {
      const int cu = (ct + ks) & 7;
      #pragma unroll
      for (int r = 0; r < 4; ++r) {
        const int gi = 128 * I + 32 * w + 16 * t + quad * 4 + r;
        const int gj = 128 * J + 16 * cu + m15;
        atomicAdd(&Gb[gi * 256 + gj], acc[t][cu][r]);
      }
    }

  if (diag) {
    #pragma unroll
    for (int p = 0; p < 8; ++p) {
      float v = rs[p];
      v += __shfl_xor(v, 1);
      v += __shfl_xor(v, 2);
      v += __shfl_xor(v, 4);
      v += __shfl_xor(v, 8);
      if ((tid & 15) == 0)
        atomicAdd(&S[b * 256 + 128 * I + p * 16 + srow], v);
    }
  }
}

// ---------------- small matvecs ---------------------------------------------
// blocks 0..511: Q row rj (bf16) + E[rj] — coalesced pw column reads.
// blocks 512..543: (mat,b) -> u or v, 16 lanes per output row (coalesced).
__global__ __launch_bounds__(256) void k_mid(const float* __restrict__ gw,
                                             const float* __restrict__ pw,
                                             const float* __restrict__ pb,
                                             const float* __restrict__ tw,
                                             const float* __restrict__ S,
                                             unsigned short* __restrict__ Qh,
                                             float* __restrict__ E,
                                             float* __restrict__ U,
                                             float* __restrict__ V) {
  __shared__ float sm[512];
  const int tid = threadIdx.x, blk = blockIdx.x;
  if (blk < 512) {
    const int rj = blk;
    sm[tid] = gw[rj * 256 + tid];
    __syncthreads();
    float q = 0.f;
    for (int p = 0; p < 256; ++p) q += sm[p] * pw[p * 256 + tid];
    Qh[rj * 256 + tid] = f2bf(q);
    sm[256 + tid] = sm[tid] * pb[tid];
    __syncthreads();
    for (int s = 128; s > 0; s >>= 1) {
      if (tid < s) sm[256 + tid] += sm[256 + tid + s];
      __syncthreads();
    }
    if (tid == 0) E[rj] = sm[256];
  } else {
    const int m = blk - 512;
    const int b = m & 15, mat = m >> 4;
    const float* Wm = mat ? pw : tw;
    float* outp = mat ? V : U;
    sm[tid] = S[b * 256 + tid];
    __syncthreads();
    const int l = tid & 15, oh = tid >> 4;
    #pragma unroll
    for (int oc = 0; oc < 16; ++oc) {
      const int o = oc * 16 + oh;
      float a = 0.f;
      #pragma unroll
      for (int j = 0; j < 16; ++j)
        a += Wm[o * 256 + l * 16 + j] * sm[l * 16 + j];
      a += __shfl_xor(a, 1);
      a += __shfl_xor(a, 2);
      a += __shfl_xor(a, 4);
      a += __shfl_xor(a, 8);
      if (l == 0) outp[b * 256 + o] = a;
    }
  }
}

// ---------------- P'' = G_b Q^T + fused Tw-contraction/bias/relu ------------
// grid (16 rj-tiles of 32, 16 batch), 256 thr / 4 waves.
// Wave w: m-rows c in [64w,64w+64) x 2 n-tiles (rj). K = 256.
// Frags load directly from global (L2-resident): G fp32->bf16 in-register.
// Epilogue also computes W2[rj] = gw_rj . v_b (8 lanes per dot).
__global__ __launch_bounds__(256) void k_p(const float* __restrict__ G,
                                           const unsigned short* __restrict__ Qh,
                                           const float* __restrict__ tw,
                                           const float* __restrict__ gw,
                                           const float* __restrict__ U,
                                           const float* __restrict__ V,
                                           const float* __restrict__ E,
                                           const float* __restrict__ tb,
                                           const float* __restrict__ gb,
                                           float* __restrict__ GR) {
  const int rjt = blockIdx.x, b = blockIdx.y;
  const int rj0 = rjt * 32;
  const int tid = threadIdx.x, w = tid >> 6, lane = tid & 63;
  const int quad = lane >> 4, m15 = lane & 15;
  const float* Gb = G + ((size_t)b << 16);

  f32x4 acc[4][2];
  #pragma unroll
  for (int mt = 0; mt < 4; ++mt) {
    acc[mt][0] = (f32x4){0.f, 0.f, 0.f, 0.f};
    acc[mt][1] = (f32x4){0.f, 0.f, 0.f, 0.f};
  }

  #pragma unroll
  for (int s = 0; s < 8; ++s) {
    const int kb = s * 32 + quad * 8;
    bf16x8 bq0 = *(const bf16x8*)(Qh + (rj0 + m15) * 256 + kb);
    bf16x8 bq1 = *(const bf16x8*)(Qh + (rj0 + 16 + m15) * 256 + kb);
    #pragma unroll
    for (int mt = 0; mt < 4; ++mt) {
      const float* ap = Gb + (64 * w + 16 * mt + m15) * 256 + kb;
      float4 g0 = *(const float4*)ap;
      float4 g1 = *(const float4*)(ap + 4);
      bf16x8 ag;
      ag[0] = (short)f2bf(g0.x); ag[1] = (short)f2bf(g0.y);
      ag[2] = (short)f2bf(g0.z); ag[3] = (short)f2bf(g0.w);
      ag[4] = (short)f2bf(g1.x); ag[5] = (short)f2bf(g1.y);
      ag[6] = (short)f2bf(g1.z); ag[7] = (short)f2bf(g1.w);
      acc[mt][0] = __builtin_amdgcn_mfma_f32_16x16x32_bf16(ag, bq0, acc[mt][0], 0, 0, 0);
      acc[mt][1] = __builtin_amdgcn_mfma_f32_16x16x32_bf16(ag, bq1, acc[mt][1], 0, 0, 0);
    }
  }

  // term[rj] = sum_c P''[c,rj] * Tw[r,c];  C/D: col = m15, row = quad*4+reg
  __shared__ float sred[32 * 4];
  __shared__ float sred2[32];
  #pragma unroll
  for (int nt = 0; nt < 2; ++nt) {
    const int rj = rj0 + 16 * nt + m15;
    const int r = rj >> 1;
    float p = 0.f;
    #pragma unroll
    for (int mt = 0; mt < 4; ++mt)
      #pragma unroll
      for (int reg = 0; reg < 4; ++reg)
        p += acc[mt][nt][reg] * tw[r * 256 + 64 * w + 16 * mt + quad * 4 + reg];
    p += __shfl_xor(p, 16);
    p += __shfl_xor(p, 32);
    if (quad == 0) sred[(16 * nt + m15) * 4 + w] = p;
  }
  // W2: 8 lanes per rj, 32 MACs each
  {
    const int oi = tid >> 3, seg = tid & 7;
    const int rj = rj0 + oi;
    float p2 = 0.f;
    #pragma unroll
    for (int i = 0; i < 32; ++i) {
      const int cp = seg * 32 + i;
      p2 += gw[rj * 256 + cp] * V[b * 256 + cp];
    }
    p2 += __shfl_xor(p2, 1);
    p2 += __shfl_xor(p2, 2);
    p2 += __shfl_xor(p2, 4);
    if (seg == 0) sred2[oi] = p2;
  }
  __syncthreads();
  if (tid < 32) {
    const int rj = rj0 + tid, r = rj >> 1;
    const float v = sred[tid * 4] + sred[tid * 4 + 1] +
                    sred[tid * 4 + 2] + sred[tid * 4 + 3];
    const float tbr = tb[r];
    const float bias = tbr * sred2[tid] +
                       (U[b * 256 + r] + 4096.0f * tbr) * E[rj] + gb[rj];
    GR[b * 512 + rj] = fmaxf(v + bias, 0.f);
  }
}

// ---------------- out = relu_g @ dw^T + db ----------------------------------
__global__ __launch_bounds__(256) void k_out(const float* __restrict__ GR,
                                             const float* __restrict__ dw,
                                             const float* __restrict__ db,
                                             float* __restrict__ out) {
  const int cch = blockIdx.x, b = blockIdx.y, tid = threadIdx.x;
  __shared__ float gl[512];
  gl[tid] = GR[b * 512 + tid];
  gl[256 + tid] = GR[b * 512 + 256 + tid];
  __syncthreads();
  const int cl = tid >> 4, l = tid & 15;
  const int c = cch * 16 + cl;
  float a = 0.f;
  #pragma unroll 8
  for (int i = 0; i < 32; ++i) {
    const int o = i * 16 + l;
    a += gl[o] * dw[c * 512 + o];
  }
  a += __shfl_xor(a, 1);
  a += __shfl_xor(a, 2);
  a += __shfl_xor(a, 4);
  a += __shfl_xor(a, 8);
  if (l == 0) out[b * 256 + c] = a + db[c];
}

extern "C" void kernel_launch(void* const* d_in, const int* in_sizes, int n_in,
                              void* d_out, int out_size, void* d_ws, size_t ws_size,
                              hipStream_t stream) {
  const float* x  = (const float*)d_in[0];
  const float* tw = (const float*)d_in[1];
  const float* tb = (const float*)d_in[2];
  const float* pw = (const float*)d_in[3];
  const float* pb = (const float*)d_in[4];
  const float* gw = (const float*)d_in[5];
  const float* gb = (const float*)d_in[6];
  const float* dw = (const float*)d_in[7];
  const float* db = (const float*)d_in[8];
  float* out = (float*)d_out;

  // workspace layout (floats): total ~4.6 MB
  float* ws = (float*)d_ws;
  float* G  = ws;                                // 16*65536      = 1048576
  float* S  = G + NB * 65536;                    // 16*256        = 4096
  float* Qf = S + NB * 256;                      // Qh: 512*256 bf16 (65536 f)
  unsigned short* Qh = (unsigned short*)Qf;
  float* E  = Qf + 65536;                        // 512
  float* U  = E + 512;                           // 16*256 = 4096
  float* V  = U + NB * 256;                      // 16*256 = 4096
  float* GR = V + NB * 256;                      // 16*512 = 8192

  // zero G + S: (1048576 + 4096) floats = 263168 float4 = 1028 blocks * 256
  k_zero<<<1028, 256, 0, stream>>>((float4*)ws);
  k_gram<<<dim3(4, 16, NB), 256, 0, stream>>>(x, G, S);
  k_mid<<<544, 256, 0, stream>>>(gw, pw, pb, tw, S, Qh, E, U, V);
  k_p<<<dim3(16, NB), 256, 0, stream>>>(G, Qh, tw, gw, U, V, E, tb, gb, GR);
  k_out<<<dim3(16, NB), 256, 0, stream>>>(GR, dw, db, out);
}

// Round 4
// 168.111 us; speedup vs baseline: 1.5839x; 1.5839x over previous
//
#include <hip/hip_runtime.h>

// nonlocal_channel_similarity: B=16, C=256, H=W=64 (N=HW=4096)
//   k_gram  : per (ks,b) block computes full 256x256 partial Gram over K-chunk
//             256; x read from HBM exactly once (64 MB). Writes bf16 slab.
//             Row sums folded in (atomicAdd on tiny S only).
//   k_reduce: sum 16 bf16 slabs -> bf16 Gh (proper [row][col] layout).
//   k_mid   : Q = gw@Pw (bf16) + E = gw.pb ; u = Tw s, v = Pw s.
//   k_p     : P'' = Gh Qh^T via MFMA (bf16 A direct load); fused
//             term = Tw-contraction + bias + relu -> GR.
//   k_out   : out = GR @ dw^T + db.

#define CC  256
#define NB  16
#define HWN 4096

typedef __attribute__((ext_vector_type(4))) float f32x4;
typedef __attribute__((ext_vector_type(8))) short bf16x8;

__device__ inline unsigned short f2bf(float f) {
  unsigned u = __float_as_uint(f);
  u += 0x7fff + ((u >> 16) & 1);   // round-to-nearest-even
  return (unsigned short)(u >> 16);
}
__device__ inline float bf2f(unsigned u) { return __uint_as_float(u << 16); }

// ---------------- Gram partials + row sums ----------------------------------
// grid (16 ks, 16 b), 1024 threads = 16 waves. Wave w: rows [16w,16w+16) x all
// 256 cols, acc[16] f32x4. LDS 256x64 bf16, double-buffered, XOR-swizzled by
// granule (8 shorts = one b128): store granule (c>>3)^(row&7) -> quarter-wave
// b128 reads land on 8 distinct 4-bank groups (2-way = free).
__global__ __launch_bounds__(1024, 4) void k_gram(const float* __restrict__ x,
                                                  unsigned short* __restrict__ slab,
                                                  float* __restrict__ S) {
  const int ks = blockIdx.x, b = blockIdx.y;
  const float* xb = x + (size_t)b * CC * HWN;
  __shared__ unsigned short As[2][256 * 64];

  const int tid = threadIdx.x, w = tid >> 6, lane = tid & 63;
  const int quad = lane >> 4, m15 = lane & 15;
  const int srow = tid >> 4;                 // 0..63
  const int scol = (tid & 15) << 2;          // 0..60 (shorts/floats)
  const int sg = scol >> 3, so = scol & 7;   // granule / offset within granule

  f32x4 acc[16];
  #pragma unroll
  for (int i = 0; i < 16; ++i) acc[i] = (f32x4){0.f, 0.f, 0.f, 0.f};
  float rs[4] = {0.f, 0.f, 0.f, 0.f};

  const int k0 = ks * 256;
  float4 ld[4];
  #pragma unroll
  for (int p = 0; p < 4; ++p)
    ld[p] = *(const float4*)(xb + (size_t)(p * 64 + srow) * HWN + k0 + scol);
  #pragma unroll
  for (int p = 0; p < 4; ++p) {
    const int row = p * 64 + srow;
    rs[p] += ld[p].x + ld[p].y + ld[p].z + ld[p].w;
    *(ushort4*)&As[0][row * 64 + ((sg ^ (row & 7)) << 3) + so] =
        make_ushort4(f2bf(ld[p].x), f2bf(ld[p].y), f2bf(ld[p].z), f2bf(ld[p].w));
  }
  __syncthreads();

  #pragma unroll
  for (int i = 0; i < 4; ++i) {
    const int cur = i & 1;
    if (i < 3) {
      const int kc = k0 + (i + 1) * 64;
      #pragma unroll
      for (int p = 0; p < 4; ++p)
        ld[p] = *(const float4*)(xb + (size_t)(p * 64 + srow) * HWN + kc + scol);
    }
    const int rowa = 16 * w + m15;
    #pragma unroll
    for (int kkg = 0; kkg < 8; kkg += 4) {   // kk/8 for kk = 0, 32
      const int ga = (kkg + quad) ^ (m15 & 7);
      bf16x8 af = *(const bf16x8*)&As[cur][rowa * 64 + ga * 8];
      #pragma unroll
      for (int ct = 0; ct < 16; ++ct) {
        bf16x8 bfr = *(const bf16x8*)&As[cur][(16 * ct + m15) * 64 + ga * 8];
        acc[ct] = __builtin_amdgcn_mfma_f32_16x16x32_bf16(af, bfr, acc[ct], 0, 0, 0);
      }
    }
    if (i < 3) {
      #pragma unroll
      for (int p = 0; p < 4; ++p) {
        const int row = p * 64 + srow;
        rs[p] += ld[p].x + ld[p].y + ld[p].z + ld[p].w;
        *(ushort4*)&As[1 - cur][row * 64 + ((sg ^ (row & 7)) << 3) + so] =
            make_ushort4(f2bf(ld[p].x), f2bf(ld[p].y), f2bf(ld[p].z), f2bf(ld[p].w));
      }
    }
    __syncthreads();
  }

  // slab store: lane-inner layout, fully coalesced 2B stores.
  unsigned short* sb = slab + ((size_t)(ks * 16 + b) << 16) + w * 4096 + lane;
  #pragma unroll
  for (int ct = 0; ct < 16; ++ct)
    #pragma unroll
    for (int reg = 0; reg < 4; ++reg)
      sb[(ct * 4 + reg) * 64] = f2bf(acc[ct][reg]);

  #pragma unroll
  for (int p = 0; p < 4; ++p) {
    float v = rs[p];
    v += __shfl_xor(v, 1);
    v += __shfl_xor(v, 2);
    v += __shfl_xor(v, 4);
    v += __shfl_xor(v, 8);
    if ((tid & 15) == 0) atomicAdd(&S[b * 256 + p * 64 + srow], v);
  }
}

// ---------------- reduce 16 slabs -> Gh (bf16, [b][row][col]) ---------------
__global__ __launch_bounds__(256) void k_reduce(const unsigned short* __restrict__ slab,
                                                unsigned short* __restrict__ Gh) {
  const int t = blockIdx.x * 256 + threadIdx.x;   // 0..131071
  const int b = t >> 13;
  const int o = (t & 8191) << 3;
  float s[8];
  #pragma unroll
  for (int i = 0; i < 8; ++i) s[i] = 0.f;
  #pragma unroll
  for (int ks = 0; ks < 16; ++ks) {
    const uint4 v = *(const uint4*)(slab + (((size_t)(ks * 16 + b)) << 16) + o);
    s[0] += bf2f(v.x & 0xffffu); s[1] += bf2f(v.x >> 16);
    s[2] += bf2f(v.y & 0xffffu); s[3] += bf2f(v.y >> 16);
    s[4] += bf2f(v.z & 0xffffu); s[5] += bf2f(v.z >> 16);
    s[6] += bf2f(v.w & 0xffffu); s[7] += bf2f(v.w >> 16);
  }
  const int wv = o >> 12, rem = o & 4095;
  const int ctreg = rem >> 6, lane6 = rem & 63;
  const int ct = ctreg >> 2, reg = ctreg & 3;
  const int quad = lane6 >> 4, m0 = lane6 & 15;
  const int row = 16 * wv + 4 * quad + reg;
  const int col = 16 * ct + m0;
  uint4 ov;
  ov.x = (unsigned)f2bf(s[0]) | ((unsigned)f2bf(s[1]) << 16);
  ov.y = (unsigned)f2bf(s[2]) | ((unsigned)f2bf(s[3]) << 16);
  ov.z = (unsigned)f2bf(s[4]) | ((unsigned)f2bf(s[5]) << 16);
  ov.w = (unsigned)f2bf(s[6]) | ((unsigned)f2bf(s[7]) << 16);
  *(uint4*)(Gh + (((size_t)b) << 16) + row * 256 + col) = ov;
}

// ---------------- small matvecs ---------------------------------------------
// blocks 0..511: Q row rj (bf16) + E[rj]. blocks 512..543: u or v per batch.
__global__ __launch_bounds__(256) void k_mid(const float* __restrict__ gw,
                                             const float* __restrict__ pw,
                                             const float* __restrict__ pb,
                                             const float* __restrict__ tw,
                                             const float* __restrict__ S,
                                             unsigned short* __restrict__ Qh,
                                             float* __restrict__ E,
                                             float* __restrict__ U,
                                             float* __restrict__ V) {
  __shared__ float sm[512];
  const int tid = threadIdx.x, blk = blockIdx.x;
  if (blk < 512) {
    const int rj = blk;
    sm[tid] = gw[rj * 256 + tid];
    __syncthreads();
    float q = 0.f;
    for (int p = 0; p < 256; ++p) q += sm[p] * pw[p * 256 + tid];
    Qh[rj * 256 + tid] = f2bf(q);
    sm[256 + tid] = sm[tid] * pb[tid];
    __syncthreads();
    for (int s = 128; s > 0; s >>= 1) {
      if (tid < s) sm[256 + tid] += sm[256 + tid + s];
      __syncthreads();
    }
    if (tid == 0) E[rj] = sm[256];
  } else {
    const int m = blk - 512;
    const int b = m & 15, mat = m >> 4;
    const float* Wm = mat ? pw : tw;
    float* outp = mat ? V : U;
    sm[tid] = S[b * 256 + tid];
    __syncthreads();
    const int l = tid & 15, oh = tid >> 4;
    #pragma unroll
    for (int oc = 0; oc < 16; ++oc) {
      const int o = oc * 16 + oh;
      float a = 0.f;
      #pragma unroll
      for (int j = 0; j < 16; ++j)
        a += Wm[o * 256 + l * 16 + j] * sm[l * 16 + j];
      a += __shfl_xor(a, 1);
      a += __shfl_xor(a, 2);
      a += __shfl_xor(a, 4);
      a += __shfl_xor(a, 8);
      if (l == 0) outp[b * 256 + o] = a;
    }
  }
}

// ---------------- P'' = Gh Qh^T + fused Tw-contraction/bias/relu ------------
// grid (16 rj-tiles of 32, 16 b), 512 thr / 8 waves. Wave w: m-rows
// [32w,32w+32). G loads are direct bf16x8 (no conversion). K = 256.
__global__ __launch_bounds__(512) void k_p(const unsigned short* __restrict__ Gh,
                                           const unsigned short* __restrict__ Qh,
                                           const float* __restrict__ tw,
                                           const float* __restrict__ gw,
                                           const float* __restrict__ U,
                                           const float* __restrict__ V,
                                           const float* __restrict__ E,
                                           const float* __restrict__ tb,
                                           const float* __restrict__ gb,
                                           float* __restrict__ GR) {
  const int rjt = blockIdx.x, b = blockIdx.y;
  const int rj0 = rjt * 32;
  const int tid = threadIdx.x, w = tid >> 6, lane = tid & 63;
  const int quad = lane >> 4, m15 = lane & 15;
  const unsigned short* Gb = Gh + ((size_t)b << 16);

  f32x4 acc[2][2];
  #pragma unroll
  for (int mt = 0; mt < 2; ++mt) {
    acc[mt][0] = (f32x4){0.f, 0.f, 0.f, 0.f};
    acc[mt][1] = (f32x4){0.f, 0.f, 0.f, 0.f};
  }

  #pragma unroll
  for (int s = 0; s < 8; ++s) {
    const int kb = s * 32 + quad * 8;
    bf16x8 bq0 = *(const bf16x8*)(Qh + (rj0 + m15) * 256 + kb);
    bf16x8 bq1 = *(const bf16x8*)(Qh + (rj0 + 16 + m15) * 256 + kb);
    #pragma unroll
    for (int mt = 0; mt < 2; ++mt) {
      bf16x8 ag = *(const bf16x8*)(Gb + (32 * w + 16 * mt + m15) * 256 + kb);
      acc[mt][0] = __builtin_amdgcn_mfma_f32_16x16x32_bf16(ag, bq0, acc[mt][0], 0, 0, 0);
      acc[mt][1] = __builtin_amdgcn_mfma_f32_16x16x32_bf16(ag, bq1, acc[mt][1], 0, 0, 0);
    }
  }

  // term[rj] partial per wave; C/D: col = m15, row = quad*4+reg
  __shared__ float sred[32 * 8];
  __shared__ float sred2[32];
  #pragma unroll
  for (int nt = 0; nt < 2; ++nt) {
    const int rj = rj0 + 16 * nt + m15;
    const int r = rj >> 1;
    float p = 0.f;
    #pragma unroll
    for (int mt = 0; mt < 2; ++mt)
      #pragma unroll
      for (int reg = 0; reg < 4; ++reg)
        p += acc[mt][nt][reg] * tw[r * 256 + 32 * w + 16 * mt + quad * 4 + reg];
    p += __shfl_xor(p, 16);
    p += __shfl_xor(p, 32);
    if (quad == 0) sred[(16 * nt + m15) * 8 + w] = p;
  }
  // W2[rj] = gw_rj . v_b : 16 lanes per rj
  {
    const int oi = tid >> 4, seg = tid & 15;
    const int rj = rj0 + oi;
    float p2 = 0.f;
    #pragma unroll
    for (int i = 0; i < 16; ++i) {
      const int cp = seg * 16 + i;
      p2 += gw[rj * 256 + cp] * V[b * 256 + cp];
    }
    p2 += __shfl_xor(p2, 1);
    p2 += __shfl_xor(p2, 2);
    p2 += __shfl_xor(p2, 4);
    p2 += __shfl_xor(p2, 8);
    if (seg == 0) sred2[oi] = p2;
  }
  __syncthreads();
  if (tid < 32) {
    const int rj = rj0 + tid, r = rj >> 1;
    float v = 0.f;
    #pragma unroll
    for (int k = 0; k < 8; ++k) v += sred[tid * 8 + k];
    const float tbr = tb[r];
    const float bias = tbr * sred2[tid] +
                       (U[b * 256 + r] + 4096.0f * tbr) * E[rj] + gb[rj];
    GR[b * 512 + rj] = fmaxf(v + bias, 0.f);
  }
}

// ---------------- out = relu_g @ dw^T + db ----------------------------------
__global__ __launch_bounds__(256) void k_out(const float* __restrict__ GR,
                                             const float* __restrict__ dw,
                                             const float* __restrict__ db,
                                             float* __restrict__ out) {
  const int cch = blockIdx.x, b = blockIdx.y, tid = threadIdx.x;
  __shared__ float gl[512];
  gl[tid] = GR[b * 512 + tid];
  gl[256 + tid] = GR[b * 512 + 256 + tid];
  __syncthreads();
  const int cl = tid >> 4, l = tid & 15;
  const int c = cch * 16 + cl;
  float a = 0.f;
  #pragma unroll 8
  for (int i = 0; i < 32; ++i) {
    const int o = i * 16 + l;
    a += gl[o] * dw[c * 512 + o];
  }
  a += __shfl_xor(a, 1);
  a += __shfl_xor(a, 2);
  a += __shfl_xor(a, 4);
  a += __shfl_xor(a, 8);
  if (l == 0) out[b * 256 + c] = a + db[c];
}

extern "C" void kernel_launch(void* const* d_in, const int* in_sizes, int n_in,
                              void* d_out, int out_size, void* d_ws, size_t ws_size,
                              hipStream_t stream) {
  const float* x  = (const float*)d_in[0];
  const float* tw = (const float*)d_in[1];
  const float* tb = (const float*)d_in[2];
  const float* pw = (const float*)d_in[3];
  const float* pb = (const float*)d_in[4];
  const float* gw = (const float*)d_in[5];
  const float* gb = (const float*)d_in[6];
  const float* dw = (const float*)d_in[7];
  const float* db = (const float*)d_in[8];
  float* out = (float*)d_out;

  // workspace: slab 33.5 MB + Gh 2 MB + Qh 0.25 MB + small fp32 (~36 MB total)
  unsigned short* slab = (unsigned short*)d_ws;
  unsigned short* Gh   = slab + ((size_t)256 << 16);   // 16 slabs x 16 b x 64K
  unsigned short* Qh   = Gh + ((size_t)16 << 16);
  float* S  = (float*)(Qh + 512 * 256);
  float* E  = S + NB * 256;
  float* U  = E + 512;
  float* V  = U + NB * 256;
  float* GR = V + NB * 256;

  hipMemsetAsync(S, 0, NB * 256 * sizeof(float), stream);
  k_gram<<<dim3(16, 16), 1024, 0, stream>>>(x, slab, S);
  k_reduce<<<512, 256, 0, stream>>>(slab, Gh);
  k_mid<<<544, 256, 0, stream>>>(gw, pw, pb, tw, S, Qh, E, U, V);
  k_p<<<dim3(16, NB), 512, 0, stream>>>(Gh, Qh, tw, gw, U, V, E, tb, gb, GR);
  k_out<<<dim3(16, NB), 256, 0, stream>>>(GR, dw, db, out);
}

// Round 5
// 152.203 us; speedup vs baseline: 1.7495x; 1.1045x over previous
//
#include <hip/hip_runtime.h>

// nonlocal_channel_similarity: B=16, C=256, H=W=64 (N=HW=4096)
//   k_gram : per (ks,b) block computes upper-triangle 16x16 sub-tiles of the
//            partial Gram over K-chunk 128; x read from HBM exactly once.
//            Compact slab (136 tiles * 512 B), coalesced uint2 stores.
//            Row-sum partials -> Spart (plain stores, no atomics).
//   k_fuse1: blocks 0..543   : reduce 32 slabs -> bf16 Gh (straight + mirror)
//            blocks 544..1055: Q = gw@Pw (bf16) + E = gw.pb
//            blocks 1056..1087: u = Tw s, v = Pw s  (s = sum of Spart)
//   k_p    : P'' = Gh Qh^T via MFMA; fused term = Tw-contraction + bias + relu
//   k_out  : out = GR @ dw^T + db

#define CC  256
#define NB  16
#define HWN 4096
#define KSPLIT 32
#define NPAIR 136   // 16x16 sub-tile pairs (w,ct), ct >= w

typedef __attribute__((ext_vector_type(4))) float f32x4;
typedef __attribute__((ext_vector_type(8))) short bf16x8;

__device__ inline unsigned short f2bf(float f) {
  unsigned u = __float_as_uint(f);
  u += 0x7fff + ((u >> 16) & 1);   // round-to-nearest-even
  return (unsigned short)(u >> 16);
}
__device__ inline float bf2f(unsigned u) { return __uint_as_float(u << 16); }

// ---------------- Gram partials (upper triangle) + row-sum partials ---------
// grid (32 ks, 16 b) = 512 blocks (2/CU), 1024 threads = 16 waves.
// Wave w: A-rows [16w,16w+16), B-tiles ct = w..15 only (G symmetric).
// LDS 256x64 bf16 double-buffered (64 KB), XOR-granule swizzle.
__global__ __launch_bounds__(1024, 4) void k_gram(const float* __restrict__ x,
                                                  unsigned short* __restrict__ slab,
                                                  float* __restrict__ Spart) {
  const int ks = blockIdx.x, b = blockIdx.y;
  const float* xb = x + (size_t)b * CC * HWN;
  __shared__ unsigned short As[2][256 * 64];

  const int tid = threadIdx.x, w = tid >> 6, lane = tid & 63;
  const int quad = lane >> 4, m15 = lane & 15;
  const int srow = tid >> 4;                 // 0..63
  const int scol = (tid & 15) << 2;          // 0..60
  const int sg = scol >> 3, so = scol & 7;

  f32x4 acc[16];
  #pragma unroll
  for (int i = 0; i < 16; ++i) acc[i] = (f32x4){0.f, 0.f, 0.f, 0.f};
  float rs[4] = {0.f, 0.f, 0.f, 0.f};

  const int k0 = ks * 128;
  float4 ld[4];
  #pragma unroll
  for (int p = 0; p < 4; ++p)
    ld[p] = *(const float4*)(xb + (size_t)(p * 64 + srow) * HWN + k0 + scol);
  #pragma unroll
  for (int p = 0; p < 4; ++p) {
    const int row = p * 64 + srow;
    rs[p] += ld[p].x + ld[p].y + ld[p].z + ld[p].w;
    *(ushort4*)&As[0][row * 64 + ((sg ^ (row & 7)) << 3) + so] =
        make_ushort4(f2bf(ld[p].x), f2bf(ld[p].y), f2bf(ld[p].z), f2bf(ld[p].w));
  }
  __syncthreads();

  #pragma unroll
  for (int i = 0; i < 2; ++i) {
    if (i < 1) {
      #pragma unroll
      for (int p = 0; p < 4; ++p)
        ld[p] = *(const float4*)(xb + (size_t)(p * 64 + srow) * HWN + k0 + 64 + scol);
    }
    const int rowa = 16 * w + m15;
    #pragma unroll
    for (int kkg = 0; kkg < 8; kkg += 4) {
      const int ga = (kkg + quad) ^ (m15 & 7);
      bf16x8 af = *(const bf16x8*)&As[i][rowa * 64 + ga * 8];
      #pragma unroll
      for (int ct = 0; ct < 16; ++ct) {
        if (ct < w) continue;   // wave-uniform triangle skip
        bf16x8 bfr = *(const bf16x8*)&As[i][(16 * ct + m15) * 64 + ga * 8];
        acc[ct] = __builtin_amdgcn_mfma_f32_16x16x32_bf16(af, bfr, acc[ct], 0, 0, 0);
      }
    }
    if (i < 1) {
      #pragma unroll
      for (int p = 0; p < 4; ++p) {
        const int row = p * 64 + srow;
        rs[p] += ld[p].x + ld[p].y + ld[p].z + ld[p].w;
        *(ushort4*)&As[1][row * 64 + ((sg ^ (row & 7)) << 3) + so] =
            make_ushort4(f2bf(ld[p].x), f2bf(ld[p].y), f2bf(ld[p].z), f2bf(ld[p].w));
      }
    }
    __syncthreads();
  }

  // compact slab: pair (w,ct) -> 512 B tile; lane writes its 4 regs as uint2.
  const int off_w = 16 * w - (w * (w - 1)) / 2;
  unsigned short* sbase = slab + ((size_t)(ks * 16 + b) * NPAIR) * 256;
  #pragma unroll
  for (int ct = 0; ct < 16; ++ct) {
    if (ct < w) continue;
    const int pid = off_w + (ct - w);
    uint2 ov;
    ov.x = (unsigned)f2bf(acc[ct][0]) | ((unsigned)f2bf(acc[ct][1]) << 16);
    ov.y = (unsigned)f2bf(acc[ct][2]) | ((unsigned)f2bf(acc[ct][3]) << 16);
    *(uint2*)(sbase + pid * 256 + lane * 4) = ov;
  }

  #pragma unroll
  for (int p = 0; p < 4; ++p) {
    float v = rs[p];
    v += __shfl_xor(v, 1);
    v += __shfl_xor(v, 2);
    v += __shfl_xor(v, 4);
    v += __shfl_xor(v, 8);
    if ((tid & 15) == 0)
      Spart[(ks * 16 + b) * 256 + p * 64 + srow] = v;
  }
}

// ---------------- fused middle ----------------------------------------------
__global__ __launch_bounds__(256) void k_fuse1(const unsigned short* __restrict__ slab,
                                               const float* __restrict__ Spart,
                                               const float* __restrict__ gw,
                                               const float* __restrict__ pw,
                                               const float* __restrict__ pb,
                                               const float* __restrict__ tw,
                                               unsigned short* __restrict__ Gh,
                                               unsigned short* __restrict__ Qh,
                                               float* __restrict__ E,
                                               float* __restrict__ U,
                                               float* __restrict__ V) {
  const int blk = blockIdx.x, tid = threadIdx.x;
  if (blk < 544) {
    // slab reduce: thread <-> (b, pair, lane)
    const int t = blk * 256 + tid;          // 0..139263
    const int b = t / 8704;
    const int rem = t % 8704;
    const int pid0 = rem >> 6, lane = rem & 63;
    int w = 0, p = pid0;
    while (p >= 16 - w) { p -= 16 - w; ++w; }
    const int ct = w + p;
    const int quad = lane >> 4, m15 = lane & 15;
    float s[4] = {0.f, 0.f, 0.f, 0.f};
    const unsigned short* sp = slab + (size_t)(b * NPAIR + pid0) * 256 + lane * 4;
    #pragma unroll
    for (int ks = 0; ks < KSPLIT; ++ks) {
      const uint2 v = *(const uint2*)(sp + (size_t)ks * 16 * NPAIR * 256);
      s[0] += bf2f(v.x & 0xffffu); s[1] += bf2f(v.x >> 16);
      s[2] += bf2f(v.y & 0xffffu); s[3] += bf2f(v.y >> 16);
    }
    unsigned short h[4];
    #pragma unroll
    for (int r = 0; r < 4; ++r) h[r] = f2bf(s[r]);
    unsigned short* Gb = Gh + ((size_t)b << 16);
    const int rb = 16 * w + quad * 4;
    const int col = 16 * ct + m15;
    #pragma unroll
    for (int r = 0; r < 4; ++r) Gb[(rb + r) * 256 + col] = h[r];
    // mirror (exact; diagonal overlap writes identical values)
    uint2 mv;
    mv.x = (unsigned)h[0] | ((unsigned)h[1] << 16);
    mv.y = (unsigned)h[2] | ((unsigned)h[3] << 16);
    *(uint2*)(Gb + col * 256 + rb) = mv;
  } else if (blk < 1056) {
    // Q row rj (bf16) + E[rj]
    const int rj = blk - 544;
    __shared__ float sm[512];
    sm[tid] = gw[rj * 256 + tid];
    __syncthreads();
    float q = 0.f;
    for (int p = 0; p < 256; ++p) q += sm[p] * pw[p * 256 + tid];
    Qh[rj * 256 + tid] = f2bf(q);
    sm[256 + tid] = sm[tid] * pb[tid];
    __syncthreads();
    for (int s = 128; s > 0; s >>= 1) {
      if (tid < s) sm[256 + tid] += sm[256 + tid + s];
      __syncthreads();
    }
    if (tid == 0) E[rj] = sm[256];
  } else {
    // u or v for batch b
    const int m = blk - 1056;
    const int b = m & 15, mat = m >> 4;
    const float* Wm = mat ? pw : tw;
    float* outp = mat ? V : U;
    __shared__ float sm[256];
    float sv = 0.f;
    #pragma unroll
    for (int ks = 0; ks < KSPLIT; ++ks)
      sv += Spart[(ks * 16 + b) * 256 + tid];
    sm[tid] = sv;
    __syncthreads();
    const int l = tid & 15, oh = tid >> 4;
    #pragma unroll
    for (int oc = 0; oc < 16; ++oc) {
      const int o = oc * 16 + oh;
      float a = 0.f;
      #pragma unroll
      for (int j = 0; j < 16; ++j)
        a += Wm[o * 256 + l * 16 + j] * sm[l * 16 + j];
      a += __shfl_xor(a, 1);
      a += __shfl_xor(a, 2);
      a += __shfl_xor(a, 4);
      a += __shfl_xor(a, 8);
      if (l == 0) outp[b * 256 + o] = a;
    }
  }
}

// ---------------- P'' = Gh Qh^T + fused Tw-contraction/bias/relu ------------
// grid (32 rj-tiles of 16, 16 b) = 512 blocks (2/CU), 256 thr / 4 waves.
// Wave w: m-rows [64w,64w+64). K = 256. Direct bf16 global loads (L2-hot).
__global__ __launch_bounds__(256) void k_p(const unsigned short* __restrict__ Gh,
                                           const unsigned short* __restrict__ Qh,
                                           const float* __restrict__ tw,
                                           const float* __restrict__ gw,
                                           const float* __restrict__ U,
                                           const float* __restrict__ V,
                                           const float* __restrict__ E,
                                           const float* __restrict__ tb,
                                           const float* __restrict__ gb,
                                           float* __restrict__ GR) {
  const int rjt = blockIdx.x, b = blockIdx.y;
  const int rj0 = rjt * 16;
  const int tid = threadIdx.x, w = tid >> 6, lane = tid & 63;
  const int quad = lane >> 4, m15 = lane & 15;
  const unsigned short* Gb = Gh + ((size_t)b << 16);

  f32x4 acc[4];
  #pragma unroll
  for (int mt = 0; mt < 4; ++mt) acc[mt] = (f32x4){0.f, 0.f, 0.f, 0.f};

  #pragma unroll
  for (int s = 0; s < 8; ++s) {
    const int kb = s * 32 + quad * 8;
    bf16x8 bq = *(const bf16x8*)(Qh + (rj0 + m15) * 256 + kb);
    #pragma unroll
    for (int mt = 0; mt < 4; ++mt) {
      bf16x8 ag = *(const bf16x8*)(Gb + (64 * w + 16 * mt + m15) * 256 + kb);
      acc[mt] = __builtin_amdgcn_mfma_f32_16x16x32_bf16(ag, bq, acc[mt], 0, 0, 0);
    }
  }

  // term[rj] = sum_c P''[c,rj]*Tw[r,c]; C/D: col = m15, row = quad*4+reg
  __shared__ float sred[16 * 4];
  __shared__ float sred2[16];
  {
    const int rj = rj0 + m15;
    const int r = rj >> 1;
    float p = 0.f;
    #pragma unroll
    for (int mt = 0; mt < 4; ++mt)
      #pragma unroll
      for (int reg = 0; reg < 4; ++reg)
        p += acc[mt][reg] * tw[r * 256 + 64 * w + 16 * mt + quad * 4 + reg];
    p += __shfl_xor(p, 16);
    p += __shfl_xor(p, 32);
    if (quad == 0) sred[m15 * 4 + w] = p;
  }
  // W2[rj] = gw_rj . v_b : 16 lanes per rj
  {
    const int oi = tid >> 4, seg = tid & 15;
    const int rj = rj0 + oi;
    float p2 = 0.f;
    #pragma unroll
    for (int i = 0; i < 16; ++i) {
      const int cp = seg * 16 + i;
      p2 += gw[rj * 256 + cp] * V[b * 256 + cp];
    }
    p2 += __shfl_xor(p2, 1);
    p2 += __shfl_xor(p2, 2);
    p2 += __shfl_xor(p2, 4);
    p2 += __shfl_xor(p2, 8);
    if (seg == 0) sred2[oi] = p2;
  }
  __syncthreads();
  if (tid < 16) {
    const int rj = rj0 + tid, r = rj >> 1;
    const float v = sred[tid * 4] + sred[tid * 4 + 1] +
                    sred[tid * 4 + 2] + sred[tid * 4 + 3];
    const float tbr = tb[r];
    const float bias = tbr * sred2[tid] +
                       (U[b * 256 + r] + 4096.0f * tbr) * E[rj] + gb[rj];
    GR[b * 512 + rj] = fmaxf(v + bias, 0.f);
  }
}

// ---------------- out = relu_g @ dw^T + db ----------------------------------
__global__ __launch_bounds__(256) void k_out(const float* __restrict__ GR,
                                             const float* __restrict__ dw,
                                             const float* __restrict__ db,
                                             float* __restrict__ out) {
  const int cch = blockIdx.x, b = blockIdx.y, tid = threadIdx.x;
  __shared__ float gl[512];
  gl[tid] = GR[b * 512 + tid];
  gl[256 + tid] = GR[b * 512 + 256 + tid];
  __syncthreads();
  const int cl = tid >> 4, l = tid & 15;
  const int c = cch * 16 + cl;
  float a = 0.f;
  #pragma unroll 8
  for (int i = 0; i < 32; ++i) {
    const int o = i * 16 + l;
    a += gl[o] * dw[c * 512 + o];
  }
  a += __shfl_xor(a, 1);
  a += __shfl_xor(a, 2);
  a += __shfl_xor(a, 4);
  a += __shfl_xor(a, 8);
  if (l == 0) out[b * 256 + c] = a + db[c];
}

extern "C" void kernel_launch(void* const* d_in, const int* in_sizes, int n_in,
                              void* d_out, int out_size, void* d_ws, size_t ws_size,
                              hipStream_t stream) {
  const float* x  = (const float*)d_in[0];
  const float* tw = (const float*)d_in[1];
  const float* tb = (const float*)d_in[2];
  const float* pw = (const float*)d_in[3];
  const float* pb = (const float*)d_in[4];
  const float* gw = (const float*)d_in[5];
  const float* gb = (const float*)d_in[6];
  const float* dw = (const float*)d_in[7];
  const float* db = (const float*)d_in[8];
  float* out = (float*)d_out;

  // workspace: slab 35.7 MB + Gh 2 MB + Qh 0.25 MB + fp32 smalls (~39 MB)
  unsigned short* slab = (unsigned short*)d_ws;                  // 512*136*256
  unsigned short* Gh   = slab + (size_t)KSPLIT * 16 * NPAIR * 256;
  unsigned short* Qh   = Gh + ((size_t)16 << 16);
  float* Spart = (float*)(Qh + 512 * 256);   // 32*16*256
  float* E  = Spart + KSPLIT * 16 * 256;
  float* U  = E + 512;
  float* V  = U + NB * 256;
  float* GR = V + NB * 256;

  k_gram<<<dim3(KSPLIT, 16), 1024, 0, stream>>>(x, slab, Spart);
  k_fuse1<<<1088, 256, 0, stream>>>(slab, Spart, gw, pw, pb, tw, Gh, Qh, E, U, V);
  k_p<<<dim3(32, NB), 256, 0, stream>>>(Gh, Qh, tw, gw, U, V, E, tb, gb, GR);
  k_out<<<dim3(16, NB), 256, 0, stream>>>(GR, dw, db, out);
}